// Round 4
// baseline (502.603 us; speedup 1.0000x reference)
//
#include <hip/hip_runtime.h>

typedef _Float16 h4 __attribute__((ext_vector_type(4)));
typedef _Float16 h8 __attribute__((ext_vector_type(8)));
typedef float f4 __attribute__((ext_vector_type(4)));

#define MFMA16(a, b, c) __builtin_amdgcn_mfma_f32_16x16x32_f16((a), (b), (c), 0, 0, 0)

static constexpr int TT  = 1024;
static constexpr int BS  = 1024;
static constexpr int LCH = 32;   // chunk length
static constexpr int NCH = 32;   // chunks (16 per half)
static constexpr size_t XTOT = (size_t)TT * BS * 128;

// workspace byte offsets
static constexpr size_t WS_WT16 = 0;       // 128x128 f16 : W_eff^T (S row-major)
static constexpr size_t WS_HF1  = 32768;   // 128x64  f16
static constexpr size_t WS_HF2  = 49152;   // 64x128  f16
static constexpr size_t WS_BW   = 65536;   // 128x64  f16
static constexpr size_t WS_EW   = 81920;   // 128x32  f16
static constexpr size_t WS_W32  = 90112;   // 128x128 f16 : (W^32)^T layout
static constexpr size_t WS_F    = 131072;                                // 32 slots f32
static constexpr size_t WS_INIT = WS_F + (size_t)NCH * BS * 128 * 4;     // 32 slots f32
static constexpr size_t WS_DRV  = WS_INIT + (size_t)NCH * BS * 128 * 4;  // 134 MB f16/half

template <typename T>
__device__ inline T ntload(const T* p) { return __builtin_nontemporal_load(p); }

// ---------------------------------------------------------------------------
// prep: W_eff (softmax+scale, stored transposed = S row-major) + f16 weights
// ---------------------------------------------------------------------------
__global__ void prep_kernel(const float* __restrict__ Aw, const float* __restrict__ As,
                            const float* __restrict__ hf1, const float* __restrict__ hf2,
                            const float* __restrict__ Bw, const float* __restrict__ Ew,
                            char* __restrict__ ws)
{
    const int tid = threadIdx.x;  // 128
    const int bid = blockIdx.x;   // 160
    if (bid < 128) {
        __shared__ float red[128];
        const int n = bid;
        const float a = Aw[n * 128 + tid];
        red[tid] = a;
        __syncthreads();
        for (int s = 64; s > 0; s >>= 1) {
            if (tid < s) red[tid] = fmaxf(red[tid], red[tid + s]);
            __syncthreads();
        }
        const float mx = red[0];
        __syncthreads();
        const float e = expf(a - mx);
        red[tid] = e;
        __syncthreads();
        for (int s = 64; s > 0; s >>= 1) {
            if (tid < s) red[tid] += red[tid + s];
            __syncthreads();
        }
        const float sm  = e / red[0];
        const float asv = As[n * 128 + tid];
        const float sc  = 1.0f - 0.1f * (1.0f / (1.0f + expf(-asv)));
        ((_Float16*)(ws + WS_WT16))[n * 128 + tid] = (_Float16)(sc * sm);
    } else {
        const int b2 = bid - 128;  // 32 blocks
        for (int i = b2 * 128 + tid; i < 8192; i += 32 * 128) {
            ((_Float16*)(ws + WS_HF1))[i] = (_Float16)hf1[i];
            ((_Float16*)(ws + WS_HF2))[i] = (_Float16)hf2[i];
            ((_Float16*)(ws + WS_BW))[i]  = (_Float16)Bw[i];
            if (i < 4096) ((_Float16*)(ws + WS_EW))[i] = (_Float16)Ew[i];
        }
    }
}

// ---------------------------------------------------------------------------
// W^32 by 5 in-LDS f16 MFMA squarings in T-layout (T = W^T row-major).
// ---------------------------------------------------------------------------
__global__ void w32_kernel(char* __restrict__ ws)
{
    const int tid  = threadIdx.x;
    const int lane = tid & 63;
    const int w    = tid >> 6;
    const int cl   = lane & 15;
    const int gq   = lane >> 4;

    __shared__ __align__(16) _Float16 Ta[128 * 128];
    __shared__ __align__(16) _Float16 Tb[128 * 128];

    const _Float16* Wt16 = (const _Float16*)(ws + WS_WT16);
    for (int i = tid; i < 2048; i += 256)
        *(h8*)&Ta[i * 8] = *(const h8*)&Wt16[i * 8];
    __syncthreads();

    for (int s = 0; s < 5; ++s) {
        const _Float16* src = (s & 1) ? Tb : Ta;
        _Float16* dst       = (s & 1) ? Ta : Tb;
        f4 acc[8][2];
#pragma unroll
        for (int mt = 0; mt < 8; ++mt)
#pragma unroll
            for (int nt = 0; nt < 2; ++nt) acc[mt][nt] = f4{};
#pragma unroll
        for (int kk = 0; kk < 4; ++kk) {
            h8 b0, b1;
#pragma unroll
            for (int j = 0; j < 8; ++j) {
                const int kr = kk * 32 + gq * 8 + j;
                b0[j] = src[kr * 128 + w * 32 + cl];
                b1[j] = src[kr * 128 + w * 32 + 16 + cl];
            }
#pragma unroll
            for (int mt = 0; mt < 8; ++mt) {
                h8 a = *(const h8*)&src[(mt * 16 + cl) * 128 + kk * 32 + gq * 8];
                acc[mt][0] = MFMA16(a, b0, acc[mt][0]);
                acc[mt][1] = MFMA16(a, b1, acc[mt][1]);
            }
        }
        __syncthreads();
#pragma unroll
        for (int mt = 0; mt < 8; ++mt)
#pragma unroll
            for (int nt = 0; nt < 2; ++nt)
#pragma unroll
                for (int r = 0; r < 4; ++r)
                    dst[(mt * 16 + gq * 4 + r) * 128 + w * 32 + nt * 16 + cl] =
                        (_Float16)acc[mt][nt][r];
        __syncthreads();
    }
    // after 5 squarings result is in Tb
    _Float16* W32 = (_Float16*)(ws + WS_W32);
    for (int i = tid; i < 2048; i += 256)
        *(h8*)&W32[i * 8] = *(const h8*)&Tb[i * 8];
}

// ---------------------------------------------------------------------------
// Phase D (per half): drive = relu(relu(md@hf1^T)@hf2^T)@Bw^T + D@Ew^T
// Block = 4 t x 16 b. Output stored TRANSPOSED per scan-lane:
// Drv[((tl*64+bt)*64 + lane)*32 + nt*4 + r] = drive[b=lane&15][n=nt*16+(lane>>4)*4+r]
// ---------------------------------------------------------------------------
__global__ __launch_bounds__(256, 4)
void drive_kernel(const float* __restrict__ Mfl, const float* __restrict__ DTi,
                  const float* __restrict__ Din, char* __restrict__ ws, int t0)
{
    const int tid  = threadIdx.x;
    const int lane = tid & 63;
    const int w    = tid >> 6;
    const int cl   = lane & 15;
    const int gq   = lane >> 4;
    const int bt   = blockIdx.x & 63;
    const int tq   = blockIdx.x >> 6;   // 0..127
    const int b0   = bt * 16;

    const _Float16* Hf1  = (const _Float16*)(ws + WS_HF1);
    const _Float16* Hf2  = (const _Float16*)(ws + WS_HF2);
    const _Float16* Bw16 = (const _Float16*)(ws + WS_BW);
    const _Float16* Ew16 = (const _Float16*)(ws + WS_EW);
    _Float16* Drv        = (_Float16*)(ws + WS_DRV);

    __shared__ __align__(16) _Float16 mds[4][16 * 64];
    __shared__ __align__(16) _Float16 dts[4][16 * 32];
    __shared__ __align__(16) _Float16 hs[4][16 * 128];   // reused as drive stage
    __shared__ __align__(16) _Float16 us[4][16 * 64];

    // ---- load 4 steps of inputs (non-temporal; role split)
    const int qrow = (tid & 127) >> 3;
    const int qc4  = (tid & 7) * 4;
    f4 pm[4], pd[4];
#pragma unroll
    for (int s = 0; s < 4; ++s) {
        const size_t t  = (size_t)(t0 + tq * 4 + s);
        const size_t rb = (t * BS + b0 + qrow) * 32 + qc4;
        pm[s] = (tid < 128) ? ntload((const f4*)&Mfl[rb]) : ntload((const f4*)&DTi[rb]);
        if (tid < 128) pd[s] = ntload((const f4*)&Din[rb]);
    }
#pragma unroll
    for (int s = 0; s < 4; ++s) {
        const int col = (tid < 128) ? qc4 : (32 + qc4);
        h4 hv;
#pragma unroll
        for (int j = 0; j < 4; ++j) hv[j] = (_Float16)pm[s][j];
        *(h4*)&mds[s][qrow * 64 + (((col >> 3) ^ (qrow & 7)) * 8) + (col & 7)] = hv;
        if (tid < 128) {
            h4 h2;
#pragma unroll
            for (int j = 0; j < 4; ++j) h2[j] = (_Float16)pd[s][j];
            *(h4*)&dts[s][qrow * 32 + (((qc4 >> 3) ^ (qrow & 3)) * 8) + (qc4 & 7)] = h2;
        }
    }

    // ---- weight B-fragments
    h8 hf1f[2][2], bwf[2][2], ewf[2], hf2f[4];
#pragma unroll
    for (int nt = 0; nt < 2; ++nt) {
        const int ng = w * 32 + nt * 16 + cl;
#pragma unroll
        for (int kk = 0; kk < 2; ++kk) {
            hf1f[nt][kk] = *(const h8*)&Hf1[ng * 64 + kk * 32 + gq * 8];
            bwf[nt][kk]  = *(const h8*)&Bw16[ng * 64 + kk * 32 + gq * 8];
        }
        ewf[nt] = *(const h8*)&Ew16[ng * 32 + gq * 8];
    }
    {
        const int ng = w * 16 + cl;
#pragma unroll
        for (int kk = 0; kk < 4; ++kk)
            hf2f[kk] = *(const h8*)&Hf2[ng * 128 + kk * 32 + gq * 8];
    }
    __syncthreads();  // B1

    // ---- GEMM1: h = relu(md @ hf1^T)
#pragma unroll
    for (int s = 0; s < 4; ++s) {
        f4 ha[2] = {};
#pragma unroll
        for (int kk = 0; kk < 2; ++kk) {
            h8 a = *(const h8*)&mds[s][cl * 64 + (((kk * 4 + gq) ^ (cl & 7)) * 8)];
            ha[0] = MFMA16(a, hf1f[0][kk], ha[0]);
            ha[1] = MFMA16(a, hf1f[1][kk], ha[1]);
        }
#pragma unroll
        for (int nt = 0; nt < 2; ++nt) {
            const int colg = w * 32 + nt * 16 + cl;
#pragma unroll
            for (int r = 0; r < 4; ++r) {
                const int row = gq * 4 + r;
                hs[s][row * 128 + (((colg >> 3) ^ (row & 15)) * 8) + (colg & 7)] =
                    (_Float16)fmaxf(ha[nt][r], 0.f);
            }
        }
    }
    __syncthreads();  // B2

    // ---- GEMM2: u = relu(h @ hf2^T)
#pragma unroll
    for (int s = 0; s < 4; ++s) {
        f4 ua = {};
#pragma unroll
        for (int kk = 0; kk < 4; ++kk) {
            h8 a = *(const h8*)&hs[s][cl * 128 + (((kk * 4 + gq) ^ (cl & 15)) * 8)];
            ua = MFMA16(a, hf2f[kk], ua);
        }
        const int colg = w * 16 + cl;
#pragma unroll
        for (int r = 0; r < 4; ++r) {
            const int row = gq * 4 + r;
            us[s][row * 64 + (((colg >> 3) ^ (row & 7)) * 8) + (colg & 7)] =
                (_Float16)fmaxf(ua[r], 0.f);
        }
    }
    __syncthreads();  // B3 (all hs reads done -> hs reusable)

    // ---- GEMM3: drive = u@Bw^T + D@Ew^T -> stage to hs[s] in (b,n)-swizzled form
#pragma unroll
    for (int s = 0; s < 4; ++s) {
        f4 acc[2] = {};
#pragma unroll
        for (int kk = 0; kk < 2; ++kk) {
            h8 a = *(const h8*)&us[s][cl * 64 + (((kk * 4 + gq) ^ (cl & 7)) * 8)];
            acc[0] = MFMA16(a, bwf[0][kk], acc[0]);
            acc[1] = MFMA16(a, bwf[1][kk], acc[1]);
        }
        {
            h8 a = *(const h8*)&dts[s][cl * 32 + ((gq ^ (cl & 3)) * 8)];
            acc[0] = MFMA16(a, ewf[0], acc[0]);
            acc[1] = MFMA16(a, ewf[1], acc[1]);
        }
#pragma unroll
        for (int nt = 0; nt < 2; ++nt) {
            const int n = w * 32 + nt * 16 + cl;
#pragma unroll
            for (int r = 0; r < 4; ++r) {
                const int b = gq * 4 + r;
                hs[s][b * 128 + (((n >> 3) ^ b) & 15) * 8 + (n & 7)] = (_Float16)acc[nt][r];
            }
        }
    }
    __syncthreads();  // B4

    // ---- pack transposed per scan-lane and store Drv (64 B per lane)
    {
        const int s2 = tid >> 6;
        const int l2 = tid & 63, c2 = l2 & 15, g2 = l2 >> 4;
        const size_t tl = (size_t)tq * 4 + s2;
        _Float16* dst = &Drv[(((size_t)tl * 64 + bt) * 64 + l2) * 32];
#pragma unroll
        for (int p = 0; p < 4; ++p) {
            h4 lo = *(const h4*)&hs[s2][c2 * 128 + (((4 * p + (g2 >> 1)) ^ c2) & 15) * 8 + (g2 & 1) * 4];
            h4 hi = *(const h4*)&hs[s2][c2 * 128 + (((4 * p + 2 + (g2 >> 1)) ^ c2) & 15) * 8 + (g2 & 1) * 4];
            h8 o;
#pragma unroll
            for (int j = 0; j < 4; ++j) { o[j] = lo[j]; o[4 + j] = hi[j]; }
            *(h8*)&dst[p * 8] = o;
        }
    }
}

// ---------------------------------------------------------------------------
// Register scan (swapped): V_new = W^T * V + drive^T per wave (16 b-rows, full 128 n).
// No barriers; wave-private LDS transpose between steps.
// FINAL=false: zero init, write F[c]. FINAL=true: init from Init[c], write X,Y.
// ---------------------------------------------------------------------------
template <bool FINAL>
__global__ __launch_bounds__(128, 1)
void scan_kernel(char* __restrict__ ws, int c0,
                 float* __restrict__ Xout, float* __restrict__ Yout)
{
    const int wslot = threadIdx.x >> 6;
    const int wid   = blockIdx.x * 2 + wslot;
    const int lane  = threadIdx.x & 63;
    const int cl = lane & 15, gq = lane >> 4;
    const int c  = c0 + (wid >> 6);
    const int bt = wid & 63;
    const int b0 = bt * 16;
    const int cloc = c & 15;

    const _Float16* Wt16 = (const _Float16*)(ws + WS_WT16);
    const _Float16* Drv  = (const _Float16*)(ws + WS_DRV);
    float* Fbuf       = (float*)(ws + WS_F);
    const float* Init = (const float*)(ws + WS_INIT);

    __shared__ __align__(16) _Float16 tb[2][16 * 128];
    _Float16* tbuf = tb[wslot];

    // A-operand: W^T fragments (static)
    h8 wf[8][4];
#pragma unroll
    for (int nt = 0; nt < 8; ++nt)
#pragma unroll
        for (int kt = 0; kt < 4; ++kt)
            wf[nt][kt] = *(const h8*)&Wt16[(nt * 16 + cl) * 128 + kt * 32 + gq * 8];

    h8 xf[4];
    if constexpr (FINAL) {
        f4 iv[8];
#pragma unroll
        for (int nt = 0; nt < 8; ++nt)
            iv[nt] = *(const f4*)&Init[((size_t)c * BS + b0 + cl) * 128 + nt * 16 + gq * 4];
#pragma unroll
        for (int nt = 0; nt < 8; ++nt) {
            h4 hv;
#pragma unroll
            for (int r = 0; r < 4; ++r) hv[r] = (_Float16)iv[nt][r];
            *(h4*)&tbuf[cl * 128 + (((nt * 2 + (gq >> 1)) ^ cl) & 15) * 8 + (gq & 1) * 4] = hv;
        }
#pragma unroll
        for (int kt = 0; kt < 4; ++kt)
            xf[kt] = *(const h8*)&tbuf[cl * 128 + (((kt * 4 + gq) ^ cl) & 15) * 8];
    } else {
#pragma unroll
        for (int kt = 0; kt < 4; ++kt) xf[kt] = h8{};
    }

    const h8* dp = (const h8*)&Drv[(((size_t)cloc * 32 * 64 + bt) * 64 + lane) * 32];
    h8 dr[4];
#pragma unroll
    for (int p = 0; p < 4; ++p) dr[p] = dp[p];

    for (int k = 0; k < LCH; ++k) {
        f4 acc[8];
#pragma unroll
        for (int p = 0; p < 4; ++p)
#pragma unroll
            for (int r = 0; r < 4; ++r) {
                acc[2 * p][r]     = (float)dr[p][r];
                acc[2 * p + 1][r] = (float)dr[p][4 + r];
            }
        if (k + 1 < LCH) {
            const h8* np = dp + (size_t)(k + 1) * 16384;  // 64*64*32 halves / 8
#pragma unroll
            for (int p = 0; p < 4; ++p) dr[p] = np[p];
        }
#pragma unroll
        for (int kt = 0; kt < 4; ++kt)
#pragma unroll
            for (int nt = 0; nt < 8; ++nt)
                acc[nt] = MFMA16(wf[nt][kt], xf[kt], acc[nt]);

        if constexpr (FINAL) {
            const size_t t = (size_t)c * LCH + k;
            float* xp = &Xout[(t * BS + b0 + cl) * 128 + gq * 4];
#pragma unroll
            for (int nt = 0; nt < 8; ++nt)
                __builtin_nontemporal_store(acc[nt], (f4*)&xp[nt * 16]);
            if (gq == 3)
                __builtin_nontemporal_store(acc[7][3], &Yout[t * BS + b0 + cl]);
        } else if (k == LCH - 1) {
#pragma unroll
            for (int nt = 0; nt < 8; ++nt)
                *(f4*)&Fbuf[((size_t)c * BS + b0 + cl) * 128 + nt * 16 + gq * 4] = acc[nt];
        }
        if (k < LCH - 1) {
#pragma unroll
            for (int nt = 0; nt < 8; ++nt) {
                h4 hv;
#pragma unroll
                for (int r = 0; r < 4; ++r) hv[r] = (_Float16)acc[nt][r];
                *(h4*)&tbuf[cl * 128 + (((nt * 2 + (gq >> 1)) ^ cl) & 15) * 8 + (gq & 1) * 4] = hv;
            }
#pragma unroll
            for (int kt = 0; kt < 4; ++kt)
                xf[kt] = *(const h8*)&tbuf[cl * 128 + (((kt * 4 + gq) ^ cl) & 15) * 8];
        }
    }
}

// ---------------------------------------------------------------------------
// carry: Init[cc] = Init[cc-1] @ W^32 + F[cc-1], register style, 1 wave/block.
// ---------------------------------------------------------------------------
__global__ __launch_bounds__(64, 1)
void carry_kernel(const float* __restrict__ x0, char* __restrict__ ws,
                  int cc_lo, int n_steps, int copy0)
{
    const int lane = threadIdx.x;
    const int cl = lane & 15, gq = lane >> 4;
    const int b0 = blockIdx.x * 16;

    const _Float16* W32 = (const _Float16*)(ws + WS_W32);
    const float* Fbuf   = (const float*)(ws + WS_F);
    float* Init         = (float*)(ws + WS_INIT);

    __shared__ __align__(16) _Float16 tbuf[16 * 128];

    h8 wf[8][4];
#pragma unroll
    for (int nt = 0; nt < 8; ++nt)
#pragma unroll
        for (int kt = 0; kt < 4; ++kt)
            wf[nt][kt] = *(const h8*)&W32[(nt * 16 + cl) * 128 + kt * 32 + gq * 8];

    h8 xf[4];
    {
        f4 iv[8];
#pragma unroll
        for (int nt = 0; nt < 8; ++nt)
            iv[nt] = *(const f4*)&x0[(size_t)(b0 + cl) * 128 + nt * 16 + gq * 4];
        if (copy0) {
#pragma unroll
            for (int nt = 0; nt < 8; ++nt)
                *(f4*)&Init[((size_t)cc_lo * BS + b0 + cl) * 128 + nt * 16 + gq * 4] = iv[nt];
        }
#pragma unroll
        for (int nt = 0; nt < 8; ++nt) {
            h4 hv;
#pragma unroll
            for (int r = 0; r < 4; ++r) hv[r] = (_Float16)iv[nt][r];
            *(h4*)&tbuf[cl * 128 + (((nt * 2 + (gq >> 1)) ^ cl) & 15) * 8 + (gq & 1) * 4] = hv;
        }
#pragma unroll
        for (int kt = 0; kt < 4; ++kt)
            xf[kt] = *(const h8*)&tbuf[cl * 128 + (((kt * 4 + gq) ^ cl) & 15) * 8];
    }

    for (int i = 1; i <= n_steps; ++i) {
        const int cc = cc_lo + i;
        f4 acc[8];
#pragma unroll
        for (int nt = 0; nt < 8; ++nt)
            acc[nt] = *(const f4*)&Fbuf[((size_t)(cc - 1) * BS + b0 + cl) * 128 + nt * 16 + gq * 4];
#pragma unroll
        for (int kt = 0; kt < 4; ++kt)
#pragma unroll
            for (int nt = 0; nt < 8; ++nt)
                acc[nt] = MFMA16(wf[nt][kt], xf[kt], acc[nt]);
#pragma unroll
        for (int nt = 0; nt < 8; ++nt)
            *(f4*)&Init[((size_t)cc * BS + b0 + cl) * 128 + nt * 16 + gq * 4] = acc[nt];
        if (i < n_steps) {
#pragma unroll
            for (int nt = 0; nt < 8; ++nt) {
                h4 hv;
#pragma unroll
                for (int r = 0; r < 4; ++r) hv[r] = (_Float16)acc[nt][r];
                *(h4*)&tbuf[cl * 128 + (((nt * 2 + (gq >> 1)) ^ cl) & 15) * 8 + (gq & 1) * 4] = hv;
            }
#pragma unroll
            for (int kt = 0; kt < 4; ++kt)
                xf[kt] = *(const h8*)&tbuf[cl * 128 + (((kt * 4 + gq) ^ cl) & 15) * 8];
        }
    }
}

// ---------------------------------------------------------------------------
extern "C" void kernel_launch(void* const* d_in, const int* in_sizes, int n_in,
                              void* d_out, int out_size, void* d_ws, size_t ws_size,
                              hipStream_t stream)
{
    const float* x_in = (const float*)d_in[0];
    const float* Mfl  = (const float*)d_in[1];
    const float* DTi  = (const float*)d_in[2];
    const float* Din  = (const float*)d_in[3];
    const float* Aw   = (const float*)d_in[4];
    const float* As   = (const float*)d_in[5];
    const float* Bw   = (const float*)d_in[6];
    const float* Ew   = (const float*)d_in[7];
    const float* hf1  = (const float*)d_in[8];
    const float* hf2  = (const float*)d_in[9];
    char* ws    = (char*)d_ws;
    float* Xout = (float*)d_out;
    float* Yout = Xout + XTOT;
    const float* Init16 = (const float*)(ws + WS_INIT) + (size_t)16 * BS * 128;

    prep_kernel<<<dim3(160), dim3(128), 0, stream>>>(Aw, As, hf1, hf2, Bw, Ew, ws);
    w32_kernel<<<dim3(1), dim3(256), 0, stream>>>(ws);

    // ---- half 1: chunks 0..15 (t 0..511)
    drive_kernel<<<dim3(128 * 64), dim3(256), 0, stream>>>(Mfl, DTi, Din, ws, 0);
    scan_kernel<false><<<dim3(512), dim3(128), 0, stream>>>(ws, 0, nullptr, nullptr);
    carry_kernel<<<dim3(64), dim3(64), 0, stream>>>(x_in, ws, 0, 16, 1);
    scan_kernel<true><<<dim3(512), dim3(128), 0, stream>>>(ws, 0, Xout, Yout);

    // ---- half 2: chunks 16..31 (t 512..1023); P1 skips chunk 31
    drive_kernel<<<dim3(128 * 64), dim3(256), 0, stream>>>(Mfl, DTi, Din, ws, 512);
    scan_kernel<false><<<dim3(480), dim3(128), 0, stream>>>(ws, 16, nullptr, nullptr);
    carry_kernel<<<dim3(64), dim3(64), 0, stream>>>(Init16, ws, 16, 15, 0);
    scan_kernel<true><<<dim3(512), dim3(128), 0, stream>>>(ws, 16, Xout, Yout);
}

// Round 5
// 482.758 us; speedup vs baseline: 1.0411x; 1.0411x over previous
//
#include <hip/hip_runtime.h>

typedef _Float16 h4 __attribute__((ext_vector_type(4)));
typedef _Float16 h8 __attribute__((ext_vector_type(8)));
typedef float f4 __attribute__((ext_vector_type(4)));

#define MFMA16(a, b, c) __builtin_amdgcn_mfma_f32_16x16x32_f16((a), (b), (c), 0, 0, 0)

static constexpr int TT  = 1024;
static constexpr int BS  = 1024;
static constexpr int LCH = 32;   // chunk length
static constexpr int NCH = 32;   // chunks
static constexpr size_t XTOT = (size_t)TT * BS * 128;

// workspace byte offsets
static constexpr size_t WS_WT16 = 0;       // 128x128 f16 : W_eff^T (S row-major)
static constexpr size_t WS_HF1  = 32768;   // 128x64  f16
static constexpr size_t WS_HF2  = 49152;   // 64x128  f16
static constexpr size_t WS_BW   = 65536;   // 128x64  f16
static constexpr size_t WS_EW   = 81920;   // 128x32  f16
static constexpr size_t WS_W32  = 90112;   // 128x128 f16 : (W^32)^T layout
static constexpr size_t WS_F    = 131072;                                // NCH slots f32
static constexpr size_t WS_INIT = WS_F + (size_t)NCH * BS * 128 * 4;     // NCH slots f32
static constexpr size_t WS_DRV  = WS_INIT + (size_t)NCH * BS * 128 * 4;  // 268 MB f16

template <typename T>
__device__ inline T ntload(const T* p) { return __builtin_nontemporal_load(p); }

// ---------------------------------------------------------------------------
// prep: W_eff (softmax+scale, stored transposed = S row-major) + f16 weights
// ---------------------------------------------------------------------------
__global__ void prep_kernel(const float* __restrict__ Aw, const float* __restrict__ As,
                            const float* __restrict__ hf1, const float* __restrict__ hf2,
                            const float* __restrict__ Bw, const float* __restrict__ Ew,
                            char* __restrict__ ws)
{
    const int tid = threadIdx.x;  // 128
    const int bid = blockIdx.x;   // 160
    if (bid < 128) {
        __shared__ float red[128];
        const int n = bid;
        const float a = Aw[n * 128 + tid];
        red[tid] = a;
        __syncthreads();
        for (int s = 64; s > 0; s >>= 1) {
            if (tid < s) red[tid] = fmaxf(red[tid], red[tid + s]);
            __syncthreads();
        }
        const float mx = red[0];
        __syncthreads();
        const float e = expf(a - mx);
        red[tid] = e;
        __syncthreads();
        for (int s = 64; s > 0; s >>= 1) {
            if (tid < s) red[tid] += red[tid + s];
            __syncthreads();
        }
        const float sm  = e / red[0];
        const float asv = As[n * 128 + tid];
        const float sc  = 1.0f - 0.1f * (1.0f / (1.0f + expf(-asv)));
        ((_Float16*)(ws + WS_WT16))[n * 128 + tid] = (_Float16)(sc * sm);
    } else {
        const int b2 = bid - 128;  // 32 blocks
        for (int i = b2 * 128 + tid; i < 8192; i += 32 * 128) {
            ((_Float16*)(ws + WS_HF1))[i] = (_Float16)hf1[i];
            ((_Float16*)(ws + WS_HF2))[i] = (_Float16)hf2[i];
            ((_Float16*)(ws + WS_BW))[i]  = (_Float16)Bw[i];
            if (i < 4096) ((_Float16*)(ws + WS_EW))[i] = (_Float16)Ew[i];
        }
    }
}

// ---------------------------------------------------------------------------
// W^32 by 5 in-LDS f16 MFMA squarings in T-layout (T = W^T row-major).
// ---------------------------------------------------------------------------
__global__ void w32_kernel(char* __restrict__ ws)
{
    const int tid  = threadIdx.x;
    const int lane = tid & 63;
    const int w    = tid >> 6;
    const int cl   = lane & 15;
    const int gq   = lane >> 4;

    __shared__ __align__(16) _Float16 Ta[128 * 128];
    __shared__ __align__(16) _Float16 Tb[128 * 128];

    const _Float16* Wt16 = (const _Float16*)(ws + WS_WT16);
    for (int i = tid; i < 2048; i += 256)
        *(h8*)&Ta[i * 8] = *(const h8*)&Wt16[i * 8];
    __syncthreads();

    for (int s = 0; s < 5; ++s) {
        const _Float16* src = (s & 1) ? Tb : Ta;
        _Float16* dst       = (s & 1) ? Ta : Tb;
        f4 acc[8][2];
#pragma unroll
        for (int mt = 0; mt < 8; ++mt)
#pragma unroll
            for (int nt = 0; nt < 2; ++nt) acc[mt][nt] = f4{};
#pragma unroll
        for (int kk = 0; kk < 4; ++kk) {
            h8 b0, b1;
#pragma unroll
            for (int j = 0; j < 8; ++j) {
                const int kr = kk * 32 + gq * 8 + j;
                b0[j] = src[kr * 128 + w * 32 + cl];
                b1[j] = src[kr * 128 + w * 32 + 16 + cl];
            }
#pragma unroll
            for (int mt = 0; mt < 8; ++mt) {
                h8 a = *(const h8*)&src[(mt * 16 + cl) * 128 + kk * 32 + gq * 8];
                acc[mt][0] = MFMA16(a, b0, acc[mt][0]);
                acc[mt][1] = MFMA16(a, b1, acc[mt][1]);
            }
        }
        __syncthreads();
#pragma unroll
        for (int mt = 0; mt < 8; ++mt)
#pragma unroll
            for (int nt = 0; nt < 2; ++nt)
#pragma unroll
                for (int r = 0; r < 4; ++r)
                    dst[(mt * 16 + gq * 4 + r) * 128 + w * 32 + nt * 16 + cl] =
                        (_Float16)acc[mt][nt][r];
        __syncthreads();
    }
    // after 5 squarings result is in Tb
    _Float16* W32 = (_Float16*)(ws + WS_W32);
    for (int i = tid; i < 2048; i += 256)
        *(h8*)&W32[i * 8] = *(const h8*)&Tb[i * 8];
}

// ---------------------------------------------------------------------------
// Phase D: drive = relu(relu(md@hf1^T)@hf2^T)@Bw^T + D@Ew^T
// Block = 4 t x 16 b. Output stored TRANSPOSED per scan-lane:
// Drv[((t*64+bt)*64 + lane)*32 + nt*4 + r] = drive[b=lane&15][n=nt*16+(lane>>4)*4+r]
// ---------------------------------------------------------------------------
__global__ __launch_bounds__(256, 4)
void drive_kernel(const float* __restrict__ Mfl, const float* __restrict__ DTi,
                  const float* __restrict__ Din, char* __restrict__ ws)
{
    const int tid  = threadIdx.x;
    const int lane = tid & 63;
    const int w    = tid >> 6;
    const int cl   = lane & 15;
    const int gq   = lane >> 4;
    const int bt   = blockIdx.x & 63;
    const int tq   = blockIdx.x >> 6;   // 0..255
    const int b0   = bt * 16;

    const _Float16* Hf1  = (const _Float16*)(ws + WS_HF1);
    const _Float16* Hf2  = (const _Float16*)(ws + WS_HF2);
    const _Float16* Bw16 = (const _Float16*)(ws + WS_BW);
    const _Float16* Ew16 = (const _Float16*)(ws + WS_EW);
    _Float16* Drv        = (_Float16*)(ws + WS_DRV);

    __shared__ __align__(16) _Float16 mds[4][16 * 64];
    __shared__ __align__(16) _Float16 dts[4][16 * 32];
    __shared__ __align__(16) _Float16 hs[4][16 * 128];   // reused as drive stage
    __shared__ __align__(16) _Float16 us[4][16 * 64];

    // ---- load 4 steps of inputs (non-temporal; role split)
    const int qrow = (tid & 127) >> 3;
    const int qc4  = (tid & 7) * 4;
    f4 pm[4], pd[4];
#pragma unroll
    for (int s = 0; s < 4; ++s) {
        const size_t t  = (size_t)tq * 4 + s;
        const size_t rb = (t * BS + b0 + qrow) * 32 + qc4;
        pm[s] = (tid < 128) ? ntload((const f4*)&Mfl[rb]) : ntload((const f4*)&DTi[rb]);
        if (tid < 128) pd[s] = ntload((const f4*)&Din[rb]);
    }
#pragma unroll
    for (int s = 0; s < 4; ++s) {
        const int col = (tid < 128) ? qc4 : (32 + qc4);
        h4 hv;
#pragma unroll
        for (int j = 0; j < 4; ++j) hv[j] = (_Float16)pm[s][j];
        *(h4*)&mds[s][qrow * 64 + (((col >> 3) ^ (qrow & 7)) * 8) + (col & 7)] = hv;
        if (tid < 128) {
            h4 h2;
#pragma unroll
            for (int j = 0; j < 4; ++j) h2[j] = (_Float16)pd[s][j];
            *(h4*)&dts[s][qrow * 32 + (((qc4 >> 3) ^ (qrow & 3)) * 8) + (qc4 & 7)] = h2;
        }
    }

    // ---- weight B-fragments
    h8 hf1f[2][2], bwf[2][2], ewf[2], hf2f[4];
#pragma unroll
    for (int nt = 0; nt < 2; ++nt) {
        const int ng = w * 32 + nt * 16 + cl;
#pragma unroll
        for (int kk = 0; kk < 2; ++kk) {
            hf1f[nt][kk] = *(const h8*)&Hf1[ng * 64 + kk * 32 + gq * 8];
            bwf[nt][kk]  = *(const h8*)&Bw16[ng * 64 + kk * 32 + gq * 8];
        }
        ewf[nt] = *(const h8*)&Ew16[ng * 32 + gq * 8];
    }
    {
        const int ng = w * 16 + cl;
#pragma unroll
        for (int kk = 0; kk < 4; ++kk)
            hf2f[kk] = *(const h8*)&Hf2[ng * 128 + kk * 32 + gq * 8];
    }
    __syncthreads();  // B1

    // ---- GEMM1: h = relu(md @ hf1^T)
#pragma unroll
    for (int s = 0; s < 4; ++s) {
        f4 ha[2] = {};
#pragma unroll
        for (int kk = 0; kk < 2; ++kk) {
            h8 a = *(const h8*)&mds[s][cl * 64 + (((kk * 4 + gq) ^ (cl & 7)) * 8)];
            ha[0] = MFMA16(a, hf1f[0][kk], ha[0]);
            ha[1] = MFMA16(a, hf1f[1][kk], ha[1]);
        }
#pragma unroll
        for (int nt = 0; nt < 2; ++nt) {
            const int colg = w * 32 + nt * 16 + cl;
#pragma unroll
            for (int r = 0; r < 4; ++r) {
                const int row = gq * 4 + r;
                hs[s][row * 128 + (((colg >> 3) ^ (row & 15)) * 8) + (colg & 7)] =
                    (_Float16)fmaxf(ha[nt][r], 0.f);
            }
        }
    }
    __syncthreads();  // B2

    // ---- GEMM2: u = relu(h @ hf2^T)
#pragma unroll
    for (int s = 0; s < 4; ++s) {
        f4 ua = {};
#pragma unroll
        for (int kk = 0; kk < 4; ++kk) {
            h8 a = *(const h8*)&hs[s][cl * 128 + (((kk * 4 + gq) ^ (cl & 15)) * 8)];
            ua = MFMA16(a, hf2f[kk], ua);
        }
        const int colg = w * 16 + cl;
#pragma unroll
        for (int r = 0; r < 4; ++r) {
            const int row = gq * 4 + r;
            us[s][row * 64 + (((colg >> 3) ^ (row & 7)) * 8) + (colg & 7)] =
                (_Float16)fmaxf(ua[r], 0.f);
        }
    }
    __syncthreads();  // B3 (all hs reads done -> hs reusable)

    // ---- GEMM3: drive = u@Bw^T + D@Ew^T -> stage to hs[s] in (b,n)-swizzled form
#pragma unroll
    for (int s = 0; s < 4; ++s) {
        f4 acc[2] = {};
#pragma unroll
        for (int kk = 0; kk < 2; ++kk) {
            h8 a = *(const h8*)&us[s][cl * 64 + (((kk * 4 + gq) ^ (cl & 7)) * 8)];
            acc[0] = MFMA16(a, bwf[0][kk], acc[0]);
            acc[1] = MFMA16(a, bwf[1][kk], acc[1]);
        }
        {
            h8 a = *(const h8*)&dts[s][cl * 32 + ((gq ^ (cl & 3)) * 8)];
            acc[0] = MFMA16(a, ewf[0], acc[0]);
            acc[1] = MFMA16(a, ewf[1], acc[1]);
        }
#pragma unroll
        for (int nt = 0; nt < 2; ++nt) {
            const int n = w * 32 + nt * 16 + cl;
#pragma unroll
            for (int r = 0; r < 4; ++r) {
                const int b = gq * 4 + r;
                hs[s][b * 128 + (((n >> 3) ^ b) & 15) * 8 + (n & 7)] = (_Float16)acc[nt][r];
            }
        }
    }
    __syncthreads();  // B4

    // ---- pack transposed per scan-lane and store Drv (64 B per lane)
    {
        const int s2 = tid >> 6;
        const int l2 = tid & 63, c2 = l2 & 15, g2 = l2 >> 4;
        const size_t t = (size_t)tq * 4 + s2;
        _Float16* dst = &Drv[(((size_t)t * 64 + bt) * 64 + l2) * 32];
#pragma unroll
        for (int p = 0; p < 4; ++p) {
            h4 lo = *(const h4*)&hs[s2][c2 * 128 + (((4 * p + (g2 >> 1)) ^ c2) & 15) * 8 + (g2 & 1) * 4];
            h4 hi = *(const h4*)&hs[s2][c2 * 128 + (((4 * p + 2 + (g2 >> 1)) ^ c2) & 15) * 8 + (g2 & 1) * 4];
            h8 o;
#pragma unroll
            for (int j = 0; j < 4; ++j) { o[j] = lo[j]; o[4 + j] = hi[j]; }
            *(h8*)&dst[p * 8] = o;
        }
    }
}

// ---------------------------------------------------------------------------
// Register scan (swapped): V_new = W^T * V + drive^T per wave (16 b, 128 n).
// No barriers; wave-private LDS transpose; Drv prefetch depth 2.
// FINAL=false: zero init, write F[c]. FINAL=true: init from Init[c], write X,Y.
// ---------------------------------------------------------------------------
template <bool FINAL>
__global__ __launch_bounds__(256, 2)
void scan_kernel(char* __restrict__ ws,
                 float* __restrict__ Xout, float* __restrict__ Yout)
{
    const int wslot = threadIdx.x >> 6;
    const int wid   = blockIdx.x * 4 + wslot;
    const int lane  = threadIdx.x & 63;
    const int cl = lane & 15, gq = lane >> 4;
    const int c  = wid >> 6;
    const int bt = wid & 63;
    const int b0 = bt * 16;

    const _Float16* Wt16 = (const _Float16*)(ws + WS_WT16);
    const _Float16* Drv  = (const _Float16*)(ws + WS_DRV);
    float* Fbuf       = (float*)(ws + WS_F);
    const float* Init = (const float*)(ws + WS_INIT);

    __shared__ __align__(16) _Float16 tb[4][16 * 128];
    _Float16* tbuf = tb[wslot];

    // A-operand: W^T fragments (static)
    h8 wf[8][4];
#pragma unroll
    for (int nt = 0; nt < 8; ++nt)
#pragma unroll
        for (int kt = 0; kt < 4; ++kt)
            wf[nt][kt] = *(const h8*)&Wt16[(nt * 16 + cl) * 128 + kt * 32 + gq * 8];

    h8 xf[4];
    if constexpr (FINAL) {
        f4 iv[8];
#pragma unroll
        for (int nt = 0; nt < 8; ++nt)
            iv[nt] = *(const f4*)&Init[((size_t)c * BS + b0 + cl) * 128 + nt * 16 + gq * 4];
#pragma unroll
        for (int nt = 0; nt < 8; ++nt) {
            h4 hv;
#pragma unroll
            for (int r = 0; r < 4; ++r) hv[r] = (_Float16)iv[nt][r];
            *(h4*)&tbuf[cl * 128 + (((nt * 2 + (gq >> 1)) ^ cl) & 15) * 8 + (gq & 1) * 4] = hv;
        }
#pragma unroll
        for (int kt = 0; kt < 4; ++kt)
            xf[kt] = *(const h8*)&tbuf[cl * 128 + (((kt * 4 + gq) ^ cl) & 15) * 8];
    } else {
#pragma unroll
        for (int kt = 0; kt < 4; ++kt) xf[kt] = h8{};
    }

    constexpr size_t STEP = 16384;  // h8 units per t-step (64*64*32/8)
    const h8* dp = (const h8*)&Drv[(((size_t)(c * LCH) * 64 + bt) * 64 + lane) * 32];
    h8 dra0, dra1, dra2, dra3, drb0, drb1, drb2, drb3;
    dra0 = dp[0]; dra1 = dp[1]; dra2 = dp[2]; dra3 = dp[3];
    drb0 = dp[STEP + 0]; drb1 = dp[STEP + 1]; drb2 = dp[STEP + 2]; drb3 = dp[STEP + 3];

#define SCAN_STEP(K, D0, D1, D2, D3)                                                     \
    {                                                                                    \
        f4 acc[8];                                                                       \
        _Pragma("unroll") for (int r = 0; r < 4; ++r) {                                  \
            acc[0][r] = (float)D0[r]; acc[1][r] = (float)D0[4 + r];                      \
            acc[2][r] = (float)D1[r]; acc[3][r] = (float)D1[4 + r];                      \
            acc[4][r] = (float)D2[r]; acc[5][r] = (float)D2[4 + r];                      \
            acc[6][r] = (float)D3[r]; acc[7][r] = (float)D3[4 + r];                      \
        }                                                                                \
        if ((K) + 2 < LCH) {                                                             \
            D0 = dp[(size_t)((K) + 2) * STEP + 0];                                       \
            D1 = dp[(size_t)((K) + 2) * STEP + 1];                                       \
            D2 = dp[(size_t)((K) + 2) * STEP + 2];                                       \
            D3 = dp[(size_t)((K) + 2) * STEP + 3];                                       \
        }                                                                                \
        _Pragma("unroll") for (int kt = 0; kt < 4; ++kt)                                 \
            _Pragma("unroll") for (int nt = 0; nt < 8; ++nt)                             \
                acc[nt] = MFMA16(wf[nt][kt], xf[kt], acc[nt]);                           \
        if constexpr (FINAL) {                                                           \
            const size_t t = (size_t)c * LCH + (K);                                      \
            float* xp = &Xout[(t * BS + b0 + cl) * 128 + gq * 4];                        \
            _Pragma("unroll") for (int nt = 0; nt < 8; ++nt)                             \
                __builtin_nontemporal_store(acc[nt], (f4*)&xp[nt * 16]);                 \
            if (gq == 3)                                                                 \
                __builtin_nontemporal_store(acc[7][3], &Yout[t * BS + b0 + cl]);         \
        } else if ((K) == LCH - 1) {                                                     \
            _Pragma("unroll") for (int nt = 0; nt < 8; ++nt)                             \
                *(f4*)&Fbuf[((size_t)c * BS + b0 + cl) * 128 + nt * 16 + gq * 4] =       \
                    acc[nt];                                                             \
        }                                                                                \
        if ((K) < LCH - 1) {                                                             \
            _Pragma("unroll") for (int nt = 0; nt < 8; ++nt) {                           \
                h4 hv;                                                                   \
                _Pragma("unroll") for (int r = 0; r < 4; ++r)                            \
                    hv[r] = (_Float16)acc[nt][r];                                        \
                *(h4*)&tbuf[cl * 128 + (((nt * 2 + (gq >> 1)) ^ cl) & 15) * 8 +          \
                            (gq & 1) * 4] = hv;                                          \
            }                                                                            \
            _Pragma("unroll") for (int kt = 0; kt < 4; ++kt)                             \
                xf[kt] = *(const h8*)&tbuf[cl * 128 + (((kt * 4 + gq) ^ cl) & 15) * 8];  \
        }                                                                                \
    }

    for (int k = 0; k < LCH; k += 2) {
        SCAN_STEP(k, dra0, dra1, dra2, dra3);
        SCAN_STEP(k + 1, drb0, drb1, drb2, drb3);
    }
#undef SCAN_STEP
}

// ---------------------------------------------------------------------------
// carry: Init[cc] = Init[cc-1] @ W^32 + F[cc-1], register style, 1 wave/block.
// ---------------------------------------------------------------------------
__global__ __launch_bounds__(64, 1)
void carry_kernel(const float* __restrict__ x0, char* __restrict__ ws, int n_steps)
{
    const int lane = threadIdx.x;
    const int cl = lane & 15, gq = lane >> 4;
    const int b0 = blockIdx.x * 16;

    const _Float16* W32 = (const _Float16*)(ws + WS_W32);
    const float* Fbuf   = (const float*)(ws + WS_F);
    float* Init         = (float*)(ws + WS_INIT);

    __shared__ __align__(16) _Float16 tbuf[16 * 128];

    h8 wf[8][4];
#pragma unroll
    for (int nt = 0; nt < 8; ++nt)
#pragma unroll
        for (int kt = 0; kt < 4; ++kt)
            wf[nt][kt] = *(const h8*)&W32[(nt * 16 + cl) * 128 + kt * 32 + gq * 8];

    h8 xf[4];
    {
        f4 iv[8];
#pragma unroll
        for (int nt = 0; nt < 8; ++nt)
            iv[nt] = *(const f4*)&x0[(size_t)(b0 + cl) * 128 + nt * 16 + gq * 4];
#pragma unroll
        for (int nt = 0; nt < 8; ++nt)
            *(f4*)&Init[(size_t)(b0 + cl) * 128 + nt * 16 + gq * 4] = iv[nt];
#pragma unroll
        for (int nt = 0; nt < 8; ++nt) {
            h4 hv;
#pragma unroll
            for (int r = 0; r < 4; ++r) hv[r] = (_Float16)iv[nt][r];
            *(h4*)&tbuf[cl * 128 + (((nt * 2 + (gq >> 1)) ^ cl) & 15) * 8 + (gq & 1) * 4] = hv;
        }
#pragma unroll
        for (int kt = 0; kt < 4; ++kt)
            xf[kt] = *(const h8*)&tbuf[cl * 128 + (((kt * 4 + gq) ^ cl) & 15) * 8];
    }

    for (int cc = 1; cc <= n_steps; ++cc) {
        f4 acc[8];
#pragma unroll
        for (int nt = 0; nt < 8; ++nt)
            acc[nt] = *(const f4*)&Fbuf[((size_t)(cc - 1) * BS + b0 + cl) * 128 + nt * 16 + gq * 4];
#pragma unroll
        for (int kt = 0; kt < 4; ++kt)
#pragma unroll
            for (int nt = 0; nt < 8; ++nt)
                acc[nt] = MFMA16(wf[nt][kt], xf[kt], acc[nt]);
#pragma unroll
        for (int nt = 0; nt < 8; ++nt)
            *(f4*)&Init[((size_t)cc * BS + b0 + cl) * 128 + nt * 16 + gq * 4] = acc[nt];
        if (cc < n_steps) {
#pragma unroll
            for (int nt = 0; nt < 8; ++nt) {
                h4 hv;
#pragma unroll
                for (int r = 0; r < 4; ++r) hv[r] = (_Float16)acc[nt][r];
                *(h4*)&tbuf[cl * 128 + (((nt * 2 + (gq >> 1)) ^ cl) & 15) * 8 + (gq & 1) * 4] = hv;
            }
#pragma unroll
            for (int kt = 0; kt < 4; ++kt)
                xf[kt] = *(const h8*)&tbuf[cl * 128 + (((kt * 4 + gq) ^ cl) & 15) * 8];
        }
    }
}

// ---------------------------------------------------------------------------
extern "C" void kernel_launch(void* const* d_in, const int* in_sizes, int n_in,
                              void* d_out, int out_size, void* d_ws, size_t ws_size,
                              hipStream_t stream)
{
    const float* x_in = (const float*)d_in[0];
    const float* Mfl  = (const float*)d_in[1];
    const float* DTi  = (const float*)d_in[2];
    const float* Din  = (const float*)d_in[3];
    const float* Aw   = (const float*)d_in[4];
    const float* As   = (const float*)d_in[5];
    const float* Bw   = (const float*)d_in[6];
    const float* Ew   = (const float*)d_in[7];
    const float* hf1  = (const float*)d_in[8];
    const float* hf2  = (const float*)d_in[9];
    char* ws    = (char*)d_ws;
    float* Xout = (float*)d_out;
    float* Yout = Xout + XTOT;

    prep_kernel<<<dim3(160), dim3(128), 0, stream>>>(Aw, As, hf1, hf2, Bw, Ew, ws);
    w32_kernel<<<dim3(1), dim3(256), 0, stream>>>(ws);

    // Phase D: all drives (fragment-transposed f16 in ws)
    drive_kernel<<<dim3(256 * 64), dim3(256), 0, stream>>>(Mfl, DTi, Din, ws);
    // P1: chunk-local scans, chunks 0..30 -> F  (31*64 waves / 4 per block)
    scan_kernel<false><<<dim3(496), dim3(256), 0, stream>>>(ws, nullptr, nullptr);
    // P2: carry propagation -> Init[0..31]
    carry_kernel<<<dim3(64), dim3(64), 0, stream>>>(x_in, ws, 31);
    // P3: true scans -> X, Y  (32*64 waves / 4 per block)
    scan_kernel<true><<<dim3(512), dim3(256), 0, stream>>>(ws, Xout, Yout);
}

// Round 6
// 456.008 us; speedup vs baseline: 1.1022x; 1.0587x over previous
//
#include <hip/hip_runtime.h>

typedef _Float16 h4 __attribute__((ext_vector_type(4)));
typedef _Float16 h8 __attribute__((ext_vector_type(8)));
typedef float f4 __attribute__((ext_vector_type(4)));

#define MFMA16(a, b, c) __builtin_amdgcn_mfma_f32_16x16x32_f16((a), (b), (c), 0, 0, 0)

static constexpr int TT  = 1024;
static constexpr int BS  = 1024;
static constexpr int LCH = 32;   // chunk length
static constexpr int NCH = 32;   // chunks
static constexpr size_t XTOT = (size_t)TT * BS * 128;

// workspace byte offsets
static constexpr size_t WS_WT16 = 0;       // 128x128 f16 : W_eff^T (S row-major)
static constexpr size_t WS_HF1  = 32768;   // 128x64  f16
static constexpr size_t WS_HF2  = 49152;   // 64x128  f16
static constexpr size_t WS_BW   = 65536;   // 128x64  f16
static constexpr size_t WS_EW   = 81920;   // 128x32  f16
static constexpr size_t WS_W32  = 90112;   // 128x128 f16 : (W^32)^T layout
static constexpr size_t WS_F    = 131072;                                // NCH slots f32
static constexpr size_t WS_INIT = WS_F + (size_t)NCH * BS * 128 * 4;     // NCH slots f32
static constexpr size_t WS_DRV  = WS_INIT + (size_t)NCH * BS * 128 * 4;  // 268 MB f16
// Drv layout: h8-index = ((t*64 + bt)*4 + p)*64 + lane  (16 B/lane dense both sides)

template <typename T>
__device__ inline T ntload(const T* p) { return __builtin_nontemporal_load(p); }

// ---------------------------------------------------------------------------
// prep: W_eff (softmax+scale, stored transposed = S row-major) + f16 weights
// ---------------------------------------------------------------------------
__global__ void prep_kernel(const float* __restrict__ Aw, const float* __restrict__ As,
                            const float* __restrict__ hf1, const float* __restrict__ hf2,
                            const float* __restrict__ Bw, const float* __restrict__ Ew,
                            char* __restrict__ ws)
{
    const int tid = threadIdx.x;  // 128
    const int bid = blockIdx.x;   // 160
    if (bid < 128) {
        __shared__ float red[128];
        const int n = bid;
        const float a = Aw[n * 128 + tid];
        red[tid] = a;
        __syncthreads();
        for (int s = 64; s > 0; s >>= 1) {
            if (tid < s) red[tid] = fmaxf(red[tid], red[tid + s]);
            __syncthreads();
        }
        const float mx = red[0];
        __syncthreads();
        const float e = expf(a - mx);
        red[tid] = e;
        __syncthreads();
        for (int s = 64; s > 0; s >>= 1) {
            if (tid < s) red[tid] += red[tid + s];
            __syncthreads();
        }
        const float sm  = e / red[0];
        const float asv = As[n * 128 + tid];
        const float sc  = 1.0f - 0.1f * (1.0f / (1.0f + expf(-asv)));
        ((_Float16*)(ws + WS_WT16))[n * 128 + tid] = (_Float16)(sc * sm);
    } else {
        const int b2 = bid - 128;  // 32 blocks
        for (int i = b2 * 128 + tid; i < 8192; i += 32 * 128) {
            ((_Float16*)(ws + WS_HF1))[i] = (_Float16)hf1[i];
            ((_Float16*)(ws + WS_HF2))[i] = (_Float16)hf2[i];
            ((_Float16*)(ws + WS_BW))[i]  = (_Float16)Bw[i];
            if (i < 4096) ((_Float16*)(ws + WS_EW))[i] = (_Float16)Ew[i];
        }
    }
}

// ---------------------------------------------------------------------------
// W^32 by 5 in-LDS f16 MFMA squarings in T-layout (T = W^T row-major).
// ---------------------------------------------------------------------------
__global__ void w32_kernel(char* __restrict__ ws)
{
    const int tid  = threadIdx.x;
    const int lane = tid & 63;
    const int w    = tid >> 6;
    const int cl   = lane & 15;
    const int gq   = lane >> 4;

    __shared__ __align__(16) _Float16 Ta[128 * 128];
    __shared__ __align__(16) _Float16 Tb[128 * 128];

    const _Float16* Wt16 = (const _Float16*)(ws + WS_WT16);
    for (int i = tid; i < 2048; i += 256)
        *(h8*)&Ta[i * 8] = *(const h8*)&Wt16[i * 8];
    __syncthreads();

    for (int s = 0; s < 5; ++s) {
        const _Float16* src = (s & 1) ? Tb : Ta;
        _Float16* dst       = (s & 1) ? Ta : Tb;
        f4 acc[8][2];
#pragma unroll
        for (int mt = 0; mt < 8; ++mt)
#pragma unroll
            for (int nt = 0; nt < 2; ++nt) acc[mt][nt] = f4{};
#pragma unroll
        for (int kk = 0; kk < 4; ++kk) {
            h8 b0, b1;
#pragma unroll
            for (int j = 0; j < 8; ++j) {
                const int kr = kk * 32 + gq * 8 + j;
                b0[j] = src[kr * 128 + w * 32 + cl];
                b1[j] = src[kr * 128 + w * 32 + 16 + cl];
            }
#pragma unroll
            for (int mt = 0; mt < 8; ++mt) {
                h8 a = *(const h8*)&src[(mt * 16 + cl) * 128 + kk * 32 + gq * 8];
                acc[mt][0] = MFMA16(a, b0, acc[mt][0]);
                acc[mt][1] = MFMA16(a, b1, acc[mt][1]);
            }
        }
        __syncthreads();
#pragma unroll
        for (int mt = 0; mt < 8; ++mt)
#pragma unroll
            for (int nt = 0; nt < 2; ++nt)
#pragma unroll
                for (int r = 0; r < 4; ++r)
                    dst[(mt * 16 + gq * 4 + r) * 128 + w * 32 + nt * 16 + cl] =
                        (_Float16)acc[mt][nt][r];
        __syncthreads();
    }
    // after 5 squarings result is in Tb
    _Float16* W32 = (_Float16*)(ws + WS_W32);
    for (int i = tid; i < 2048; i += 256)
        *(h8*)&W32[i * 8] = *(const h8*)&Tb[i * 8];
}

// ---------------------------------------------------------------------------
// Phase D (swapped operands): h^T = hf1*md^T, u^T = hf2*h^T,
// drive^T = Bw*u^T + Ew*D^T.  Weight frags = A-operands, data = B-operands.
// GEMM3 output frag IS the scan's acc layout -> store h8 direct, coalesced.
// Block = 4 t x 16 b.
// ---------------------------------------------------------------------------
__global__ __launch_bounds__(256, 4)
void drive_kernel(const float* __restrict__ Mfl, const float* __restrict__ DTi,
                  const float* __restrict__ Din, char* __restrict__ ws)
{
    const int tid  = threadIdx.x;
    const int lane = tid & 63;
    const int w    = tid >> 6;
    const int cl   = lane & 15;
    const int gq   = lane >> 4;
    const int bt   = blockIdx.x & 63;
    const int tq   = blockIdx.x >> 6;   // 0..255
    const int b0   = bt * 16;

    const _Float16* Hf1  = (const _Float16*)(ws + WS_HF1);
    const _Float16* Hf2  = (const _Float16*)(ws + WS_HF2);
    const _Float16* Bw16 = (const _Float16*)(ws + WS_BW);
    const _Float16* Ew16 = (const _Float16*)(ws + WS_EW);
    _Float16* Drv        = (_Float16*)(ws + WS_DRV);

    __shared__ __align__(16) _Float16 mds[4][16 * 64];
    __shared__ __align__(16) _Float16 dts[4][16 * 32];
    __shared__ __align__(16) _Float16 hs[4][16 * 128];
    __shared__ __align__(16) _Float16 us[4][16 * 64];

    // ---- load 4 steps of inputs (non-temporal; role split)
    const int qrow = (tid & 127) >> 3;
    const int qc4  = (tid & 7) * 4;
    f4 pm[4], pd[4];
#pragma unroll
    for (int s = 0; s < 4; ++s) {
        const size_t t  = (size_t)tq * 4 + s;
        const size_t rb = (t * BS + b0 + qrow) * 32 + qc4;
        pm[s] = (tid < 128) ? ntload((const f4*)&Mfl[rb]) : ntload((const f4*)&DTi[rb]);
        if (tid < 128) pd[s] = ntload((const f4*)&Din[rb]);
    }
#pragma unroll
    for (int s = 0; s < 4; ++s) {
        const int col = (tid < 128) ? qc4 : (32 + qc4);
        h4 hv;
#pragma unroll
        for (int j = 0; j < 4; ++j) hv[j] = (_Float16)pm[s][j];
        *(h4*)&mds[s][qrow * 64 + (((col >> 3) ^ (qrow & 7)) * 8) + (col & 7)] = hv;
        if (tid < 128) {
            h4 h2;
#pragma unroll
            for (int j = 0; j < 4; ++j) h2[j] = (_Float16)pd[s][j];
            *(h4*)&dts[s][qrow * 32 + (((qc4 >> 3) ^ (qrow & 3)) * 8) + (qc4 & 7)] = h2;
        }
    }

    // ---- weight fragments (used as A-operands; same loads as before)
    h8 hf1f[2][2], bwf[2][2], ewf[2], hf2f[4];
#pragma unroll
    for (int nt = 0; nt < 2; ++nt) {
        const int ng = w * 32 + nt * 16 + cl;
#pragma unroll
        for (int kk = 0; kk < 2; ++kk) {
            hf1f[nt][kk] = *(const h8*)&Hf1[ng * 64 + kk * 32 + gq * 8];
            bwf[nt][kk]  = *(const h8*)&Bw16[ng * 64 + kk * 32 + gq * 8];
        }
        ewf[nt] = *(const h8*)&Ew16[ng * 32 + gq * 8];
    }
    {
        const int ng = w * 16 + cl;
#pragma unroll
        for (int kk = 0; kk < 4; ++kk)
            hf2f[kk] = *(const h8*)&Hf2[ng * 128 + kk * 32 + gq * 8];
    }
    __syncthreads();  // B1

    // ---- GEMM1: h^T = hf1 * md^T ; lane -> h[n=w*32+nt*16+gq*4+r][b=cl]
#pragma unroll
    for (int s = 0; s < 4; ++s) {
        f4 ha[2] = {};
#pragma unroll
        for (int kk = 0; kk < 2; ++kk) {
            h8 a = *(const h8*)&mds[s][cl * 64 + (((kk * 4 + gq) ^ (cl & 7)) * 8)];
            ha[0] = MFMA16(hf1f[0][kk], a, ha[0]);
            ha[1] = MFMA16(hf1f[1][kk], a, ha[1]);
        }
#pragma unroll
        for (int nt = 0; nt < 2; ++nt) {
            const int nb8 = w * 4 + nt * 2 + (gq >> 1);
            h4 hv;
#pragma unroll
            for (int r = 0; r < 4; ++r) hv[r] = (_Float16)fmaxf(ha[nt][r], 0.f);
            *(h4*)&hs[s][cl * 128 + ((nb8 ^ cl) & 15) * 8 + (gq & 1) * 4] = hv;
        }
    }
    __syncthreads();  // B2

    // ---- GEMM2: u^T = hf2 * h^T ; lane -> u[n=w*16+gq*4+r][b=cl]
#pragma unroll
    for (int s = 0; s < 4; ++s) {
        f4 ua = {};
#pragma unroll
        for (int kt = 0; kt < 4; ++kt) {
            h8 a = *(const h8*)&hs[s][cl * 128 + (((kt * 4 + gq) ^ cl) & 15) * 8];
            ua = MFMA16(hf2f[kt], a, ua);
        }
        const int nb8 = w * 2 + (gq >> 1);
        h4 hv;
#pragma unroll
        for (int r = 0; r < 4; ++r) hv[r] = (_Float16)fmaxf(ua[r], 0.f);
        *(h4*)&us[s][cl * 64 + ((nb8 ^ (cl & 7)) & 7) * 8 + (gq & 1) * 4] = hv;
    }
    __syncthreads();  // B3

    // ---- GEMM3: drive^T = Bw*u^T + Ew*D^T -> h8 store, scan-ready layout
#pragma unroll
    for (int s = 0; s < 4; ++s) {
        f4 acc[2] = {};
#pragma unroll
        for (int kk = 0; kk < 2; ++kk) {
            h8 a = *(const h8*)&us[s][cl * 64 + (((kk * 4 + gq) ^ (cl & 7)) & 7) * 8];
            acc[0] = MFMA16(bwf[0][kk], a, acc[0]);
            acc[1] = MFMA16(bwf[1][kk], a, acc[1]);
        }
        {
            h8 a = *(const h8*)&dts[s][cl * 32 + ((gq ^ (cl & 3)) * 8)];
            acc[0] = MFMA16(ewf[0], a, acc[0]);
            acc[1] = MFMA16(ewf[1], a, acc[1]);
        }
        h8 o;
#pragma unroll
        for (int r = 0; r < 4; ++r) { o[r] = (_Float16)acc[0][r]; o[4 + r] = (_Float16)acc[1][r]; }
        const size_t t = (size_t)tq * 4 + s;
        *(h8*)&Drv[((t * 64 + bt) * 256 + tid) * 8] = o;   // [t][bt][p=w][lane], dense
    }
}

// ---------------------------------------------------------------------------
// Register scan (swapped): V_new = W^T * V + drive^T per wave (16 b, 128 n).
// No barriers; wave-private LDS transpose; coalesced Drv loads, prefetch 2.
// FINAL=false: zero init, write F[c]. FINAL=true: init from Init[c], write X,Y.
// ---------------------------------------------------------------------------
template <bool FINAL>
__global__ __launch_bounds__(256, 2)
void scan_kernel(char* __restrict__ ws,
                 float* __restrict__ Xout, float* __restrict__ Yout)
{
    const int wslot = threadIdx.x >> 6;
    const int wid   = blockIdx.x * 4 + wslot;
    const int lane  = threadIdx.x & 63;
    const int cl = lane & 15, gq = lane >> 4;
    const int c  = wid >> 6;
    const int bt = wid & 63;
    const int b0 = bt * 16;

    const _Float16* Wt16 = (const _Float16*)(ws + WS_WT16);
    const _Float16* Drv  = (const _Float16*)(ws + WS_DRV);
    float* Fbuf       = (float*)(ws + WS_F);
    const float* Init = (const float*)(ws + WS_INIT);

    __shared__ __align__(16) _Float16 tb[4][16 * 128];
    _Float16* tbuf = tb[wslot];

    // A-operand: W^T fragments (static)
    h8 wf[8][4];
#pragma unroll
    for (int nt = 0; nt < 8; ++nt)
#pragma unroll
        for (int kt = 0; kt < 4; ++kt)
            wf[nt][kt] = *(const h8*)&Wt16[(nt * 16 + cl) * 128 + kt * 32 + gq * 8];

    h8 xf[4];
    if constexpr (FINAL) {
        f4 iv[8];
#pragma unroll
        for (int nt = 0; nt < 8; ++nt)
            iv[nt] = *(const f4*)&Init[((size_t)c * BS + b0 + cl) * 128 + nt * 16 + gq * 4];
#pragma unroll
        for (int nt = 0; nt < 8; ++nt) {
            h4 hv;
#pragma unroll
            for (int r = 0; r < 4; ++r) hv[r] = (_Float16)iv[nt][r];
            *(h4*)&tbuf[cl * 128 + (((nt * 2 + (gq >> 1)) ^ cl) & 15) * 8 + (gq & 1) * 4] = hv;
        }
#pragma unroll
        for (int kt = 0; kt < 4; ++kt)
            xf[kt] = *(const h8*)&tbuf[cl * 128 + (((kt * 4 + gq) ^ cl) & 15) * 8];
    } else {
#pragma unroll
        for (int kt = 0; kt < 4; ++kt) xf[kt] = h8{};
    }

    constexpr size_t STEP = 16384;  // h8 units per t-step (64*4*64)
    // Drv h8-index: ((t*64+bt)*4 + p)*64 + lane ; p-loads are lane-dense 1 KB
    const h8* dp = (const h8*)Drv + (((size_t)(c * LCH) * 64 + bt) * 4) * 64 + lane;
    h8 dra0, dra1, dra2, dra3, drb0, drb1, drb2, drb3;
    dra0 = dp[0];          dra1 = dp[64];          dra2 = dp[128];          dra3 = dp[192];
    drb0 = dp[STEP];       drb1 = dp[STEP + 64];   drb2 = dp[STEP + 128];   drb3 = dp[STEP + 192];

#define SCAN_STEP(K, D0, D1, D2, D3)                                                     \
    {                                                                                    \
        f4 acc[8];                                                                       \
        _Pragma("unroll") for (int r = 0; r < 4; ++r) {                                  \
            acc[0][r] = (float)D0[r]; acc[1][r] = (float)D0[4 + r];                      \
            acc[2][r] = (float)D1[r]; acc[3][r] = (float)D1[4 + r];                      \
            acc[4][r] = (float)D2[r]; acc[5][r] = (float)D2[4 + r];                      \
            acc[6][r] = (float)D3[r]; acc[7][r] = (float)D3[4 + r];                      \
        }                                                                                \
        if ((K) + 2 < LCH) {                                                             \
            D0 = dp[(size_t)((K) + 2) * STEP + 0];                                       \
            D1 = dp[(size_t)((K) + 2) * STEP + 64];                                      \
            D2 = dp[(size_t)((K) + 2) * STEP + 128];                                     \
            D3 = dp[(size_t)((K) + 2) * STEP + 192];                                     \
        }                                                                                \
        _Pragma("unroll") for (int kt = 0; kt < 4; ++kt)                                 \
            _Pragma("unroll") for (int nt = 0; nt < 8; ++nt)                             \
                acc[nt] = MFMA16(wf[nt][kt], xf[kt], acc[nt]);                           \
        if constexpr (FINAL) {                                                           \
            const size_t t = (size_t)c * LCH + (K);                                      \
            float* xp = &Xout[(t * BS + b0 + cl) * 128 + gq * 4];                        \
            _Pragma("unroll") for (int nt = 0; nt < 8; ++nt)                             \
                __builtin_nontemporal_store(acc[nt], (f4*)&xp[nt * 16]);                 \
            if (gq == 3)                                                                 \
                __builtin_nontemporal_store(acc[7][3], &Yout[t * BS + b0 + cl]);         \
        } else if ((K) == LCH - 1) {                                                     \
            _Pragma("unroll") for (int nt = 0; nt < 8; ++nt)                             \
                *(f4*)&Fbuf[((size_t)c * BS + b0 + cl) * 128 + nt * 16 + gq * 4] =       \
                    acc[nt];                                                             \
        }                                                                                \
        if ((K) < LCH - 1) {                                                             \
            _Pragma("unroll") for (int nt = 0; nt < 8; ++nt) {                           \
                h4 hv;                                                                   \
                _Pragma("unroll") for (int r = 0; r < 4; ++r)                            \
                    hv[r] = (_Float16)acc[nt][r];                                        \
                *(h4*)&tbuf[cl * 128 + (((nt * 2 + (gq >> 1)) ^ cl) & 15) * 8 +          \
                            (gq & 1) * 4] = hv;                                          \
            }                                                                            \
            _Pragma("unroll") for (int kt = 0; kt < 4; ++kt)                             \
                xf[kt] = *(const h8*)&tbuf[cl * 128 + (((kt * 4 + gq) ^ cl) & 15) * 8];  \
        }                                                                                \
    }

    for (int k = 0; k < LCH; k += 2) {
        SCAN_STEP(k, dra0, dra1, dra2, dra3);
        SCAN_STEP(k + 1, drb0, drb1, drb2, drb3);
    }
#undef SCAN_STEP
}

// ---------------------------------------------------------------------------
// carry: Init[cc] = Init[cc-1] @ W^32 + F[cc-1], register style, 1 wave/block.
// ---------------------------------------------------------------------------
__global__ __launch_bounds__(64, 1)
void carry_kernel(const float* __restrict__ x0, char* __restrict__ ws, int n_steps)
{
    const int lane = threadIdx.x;
    const int cl = lane & 15, gq = lane >> 4;
    const int b0 = blockIdx.x * 16;

    const _Float16* W32 = (const _Float16*)(ws + WS_W32);
    const float* Fbuf   = (const float*)(ws + WS_F);
    float* Init         = (float*)(ws + WS_INIT);

    __shared__ __align__(16) _Float16 tbuf[16 * 128];

    h8 wf[8][4];
#pragma unroll
    for (int nt = 0; nt < 8; ++nt)
#pragma unroll
        for (int kt = 0; kt < 4; ++kt)
            wf[nt][kt] = *(const h8*)&W32[(nt * 16 + cl) * 128 + kt * 32 + gq * 8];

    h8 xf[4];
    {
        f4 iv[8];
#pragma unroll
        for (int nt = 0; nt < 8; ++nt)
            iv[nt] = *(const f4*)&x0[(size_t)(b0 + cl) * 128 + nt * 16 + gq * 4];
#pragma unroll
        for (int nt = 0; nt < 8; ++nt)
            *(f4*)&Init[(size_t)(b0 + cl) * 128 + nt * 16 + gq * 4] = iv[nt];
#pragma unroll
        for (int nt = 0; nt < 8; ++nt) {
            h4 hv;
#pragma unroll
            for (int r = 0; r < 4; ++r) hv[r] = (_Float16)iv[nt][r];
            *(h4*)&tbuf[cl * 128 + (((nt * 2 + (gq >> 1)) ^ cl) & 15) * 8 + (gq & 1) * 4] = hv;
        }
#pragma unroll
        for (int kt = 0; kt < 4; ++kt)
            xf[kt] = *(const h8*)&tbuf[cl * 128 + (((kt * 4 + gq) ^ cl) & 15) * 8];
    }

    for (int cc = 1; cc <= n_steps; ++cc) {
        f4 acc[8];
#pragma unroll
        for (int nt = 0; nt < 8; ++nt)
            acc[nt] = *(const f4*)&Fbuf[((size_t)(cc - 1) * BS + b0 + cl) * 128 + nt * 16 + gq * 4];
#pragma unroll
        for (int kt = 0; kt < 4; ++kt)
#pragma unroll
            for (int nt = 0; nt < 8; ++nt)
                acc[nt] = MFMA16(wf[nt][kt], xf[kt], acc[nt]);
#pragma unroll
        for (int nt = 0; nt < 8; ++nt)
            *(f4*)&Init[((size_t)cc * BS + b0 + cl) * 128 + nt * 16 + gq * 4] = acc[nt];
        if (cc < n_steps) {
#pragma unroll
            for (int nt = 0; nt < 8; ++nt) {
                h4 hv;
#pragma unroll
                for (int r = 0; r < 4; ++r) hv[r] = (_Float16)acc[nt][r];
                *(h4*)&tbuf[cl * 128 + (((nt * 2 + (gq >> 1)) ^ cl) & 15) * 8 + (gq & 1) * 4] = hv;
            }
#pragma unroll
            for (int kt = 0; kt < 4; ++kt)
                xf[kt] = *(const h8*)&tbuf[cl * 128 + (((kt * 4 + gq) ^ cl) & 15) * 8];
        }
    }
}

// ---------------------------------------------------------------------------
extern "C" void kernel_launch(void* const* d_in, const int* in_sizes, int n_in,
                              void* d_out, int out_size, void* d_ws, size_t ws_size,
                              hipStream_t stream)
{
    const float* x_in = (const float*)d_in[0];
    const float* Mfl  = (const float*)d_in[1];
    const float* DTi  = (const float*)d_in[2];
    const float* Din  = (const float*)d_in[3];
    const float* Aw   = (const float*)d_in[4];
    const float* As   = (const float*)d_in[5];
    const float* Bw   = (const float*)d_in[6];
    const float* Ew   = (const float*)d_in[7];
    const float* hf1  = (const float*)d_in[8];
    const float* hf2  = (const float*)d_in[9];
    char* ws    = (char*)d_ws;
    float* Xout = (float*)d_out;
    float* Yout = Xout + XTOT;

    prep_kernel<<<dim3(160), dim3(128), 0, stream>>>(Aw, As, hf1, hf2, Bw, Ew, ws);
    w32_kernel<<<dim3(1), dim3(256), 0, stream>>>(ws);

    // Phase D: all drives (scan-ready layout, dense 16 B/lane)
    drive_kernel<<<dim3(256 * 64), dim3(256), 0, stream>>>(Mfl, DTi, Din, ws);
    // P1: chunk-local scans, chunks 0..30 -> F
    scan_kernel<false><<<dim3(496), dim3(256), 0, stream>>>(ws, nullptr, nullptr);
    // P2: carry propagation -> Init[0..31]
    carry_kernel<<<dim3(64), dim3(64), 0, stream>>>(x_in, ws, 31);
    // P3: true scans -> X, Y
    scan_kernel<true><<<dim3(512), dim3(256), 0, stream>>>(ws, Xout, Yout);
}